// Round 9
// baseline (36.520 us; speedup 1.0000x reference)
//
#include <hip/hip_runtime.h>

#define ODE_UNFOLDS 6
#define LTC_EPS 1e-8f

// One lane per (batch b, unit u); adjacent lanes hold the coupled pair {j,j+d}.
// State: (num, r), v = num*r.
//
// Wiring identity (MemoryCellWiring): erev = -mask, sensory_erev = +smask,
// so WE_s = -W_s, WE_c = -W_c, sWE = +sW. With num/den scaled through by
// P = (1+es)(1+ex):
//   den' = K0 + Ks*es + Kx*ex + db*es*ex      (Horner-by-late-ex, 3 fma)
//   num' = (t+db)*P - den'                    (!! the whole Q-side collapses)
// where t = cm*v + nb, and nb+db = (gv+den0) + 2*sW*ss is ONE base fma.
// Per unfold: 2 exp + 1 rcp (trans) + ~10 full-rate scalar ops.
// Base block software-pipelined one timestep ahead; partner's cross-exp
// exchanged by quad_perm DPP (lane XOR 1).

__device__ __forceinline__ float swap_pair(float x) {
    return __int_as_float(
        __builtin_amdgcn_mov_dpp(__float_as_int(x), 0xB1, 0xF, 0xF, true));
}

struct Base { float db, nbdb, K0, Ks, Kx; };

__global__ __launch_bounds__(64)
void ltc_lane_kernel(const float* __restrict__ inputs,
                     const float* __restrict__ input_w, const float* __restrict__ input_b,
                     const float* __restrict__ output_w, const float* __restrict__ output_b,
                     const float* __restrict__ gleak, const float* __restrict__ vleak,
                     const float* __restrict__ cm,
                     const float* __restrict__ w, const float* __restrict__ mu,
                     const float* __restrict__ sigma, const float* __restrict__ erev,
                     const float* __restrict__ sw, const float* __restrict__ smu,
                     const float* __restrict__ ssig, const float* __restrict__ serev,
                     float* __restrict__ out,
                     int B, int T, int d)
{
    const int tid = blockIdx.x * blockDim.x + threadIdx.x;
    const int units = 2 * d;
    if (tid >= B * units) return;

    const int pairIdx = tid >> 1;
    const int h = tid & 1;                 // 0 -> unit j, 1 -> unit j+d
    const int b = pairIdx / d;
    const int j = pairIdx - b * d;
    const int u  = j + h * d;              // my unit
    const int pu = j + (1 - h) * d;        // partner unit

    const float LOG2E = 1.4426950408889634f;

    // self synapse u->u
    float A_s, C_s, W_s;
    {
        int i = u * units + u;
        float sg = sigma[i], m = mu[i];
        A_s = -sg * LOG2E; C_s = m * sg * LOG2E;
        W_s = w[i] * (-erev[i]);           // = +W (erev = -1 on this synapse)
    }
    // incoming cross synapse pu->u
    float W_c;
    {
        int i = pu * units + u;
        W_c = w[i] * (-erev[i]);           // = +W
    }
    // outgoing cross synapse u->pu (we evaluate its exp from our own v)
    float A_o, C_o;
    {
        int i = u * units + pu;
        float sg = sigma[i], m = mu[i];
        A_o = -sg * LOG2E; C_o = m * sg * LOG2E;
    }
    const float Wsum = W_s + W_c;

    // sensory synapse j -> u (serev = +1), input affine folded in
    float siA, siC, sW;
    {
        int i = j * units + u;
        float sg = ssig[i], m = smu[i];
        float sA = -sg * LOG2E, sC = m * sg * LOG2E;
        const float iw = input_w[j], ib = input_b[j];
        siA = iw * sA; siC = ib * sA + sC;
        sW = sw[i] * serev[i];             // = +sW
    }

    const float cmu = cm[u] * (float)ODE_UNFOLDS;
    const float gl  = gleak[u];
    const float gv  = gl * vleak[u];
    const float den0 = cmu + gl + LTC_EPS;
    const float sW2 = 2.f * sW;
    const float gvden0 = gv + den0;

    const float* __restrict__ xin = inputs + (size_t)b * T * d + j;

    auto make_base = [&](float x) -> Base {
        const float e  = __builtin_amdgcn_exp2f(fmaf(x, siA, siC));
        const float ss = __builtin_amdgcn_rcpf(1.f + e);
        Base bb;
        bb.db   = fmaf(sW,  ss, den0);
        bb.nbdb = fmaf(sW2, ss, gvden0);   // nb + db in one fma
        bb.K0 = bb.db + Wsum;
        bb.Ks = bb.db + W_c;
        bb.Kx = bb.db + W_s;
        return bb;
    };

    // recurrence state: v = num * r
    float num = 0.f, r = 1.f;

    const int TU = 4;
    float xbuf[TU];
#pragma unroll
    for (int k = 0; k < TU; ++k) xbuf[k] = xin[(size_t)k * d];

    Base cur = make_base(xbuf[0]);

    for (int g = 0; g < T; g += TU) {
        float xnext[TU];
        if (g + TU < T) {
#pragma unroll
            for (int k = 0; k < TU; ++k) xnext[k] = xin[(size_t)(g + TU + k) * d];
        } else {
#pragma unroll
            for (int k = 0; k < TU; ++k) xnext[k] = 0.f;
        }

#pragma unroll
        for (int k = 0; k < TU; ++k) {
            // next timestep's base, issued early so it hides under unfold stalls
            const float xn1 = (k + 1 < TU) ? xbuf[k + 1] : xnext[0];
            const Base nxt = make_base(xn1);

#pragma unroll
            for (int uu = 0; uu < ODE_UNFOLDS; ++uu) {
                const float cn = cmu * num;          // parallel w/ rcp
                const float ts = A_s * num;
                const float to = A_o * num;
                const float argo = fmaf(to, r, C_o); // outgoing first (+dpp)
                const float args = fmaf(ts, r, C_s);
                const float eo = __builtin_amdgcn_exp2f(argo);
                const float es = __builtin_amdgcn_exp2f(args);
                const float ex = swap_pair(eo);      // partner's exp (late)

                const float tdb = fmaf(cn, r, cur.nbdb);  // t + db
                const float pe  = 1.f + es;
                const float P1  = fmaf(cur.Ks, es, cur.K0);
                const float P2  = fmaf(cur.db, es, cur.Kx);
                const float Pp  = fmaf(pe, ex, pe);       // (1+es)(1+ex)
                const float den = fmaf(P2, ex, P1);

                num = fmaf(tdb, Pp, -den);           // (t+db)*P - den'
                r   = __builtin_amdgcn_rcpf(den);
            }

            cur = nxt;
        }

#pragma unroll
        for (int k = 0; k < TU; ++k) xbuf[k] = xnext[k];
    }

    if (h == 0) {
        const float v = num * r;
        out[(size_t)b * d + j] = fmaf(v, output_w[j], output_b[j]);
    }
}

extern "C" void kernel_launch(void* const* d_in, const int* in_sizes, int n_in,
                              void* d_out, int out_size, void* d_ws, size_t ws_size,
                              hipStream_t stream) {
    const float* inputs   = (const float*)d_in[0];
    const float* input_w  = (const float*)d_in[1];
    const float* input_b  = (const float*)d_in[2];
    const float* output_w = (const float*)d_in[3];
    const float* output_b = (const float*)d_in[4];
    const float* gleak    = (const float*)d_in[5];
    const float* vleak    = (const float*)d_in[6];
    const float* cm       = (const float*)d_in[7];
    const float* w        = (const float*)d_in[8];
    const float* mu       = (const float*)d_in[9];
    const float* sigma    = (const float*)d_in[10];
    const float* erev     = (const float*)d_in[11];
    const float* sw       = (const float*)d_in[12];
    const float* smu      = (const float*)d_in[13];
    const float* ssig     = (const float*)d_in[14];
    const float* serev    = (const float*)d_in[15];
    float* out = (float*)d_out;

    const int d = in_sizes[1];            // input_w has shape (d,)
    const int B = out_size / d;           // out is (B, d)
    const int T = in_sizes[0] / (B * d);  // inputs is (B, T, d)

    const int total = B * 2 * d;          // one thread per (b, unit)
    const int block = 64;
    const int grid = (total + block - 1) / block;
    ltc_lane_kernel<<<grid, block, 0, stream>>>(
        inputs, input_w, input_b, output_w, output_b,
        gleak, vleak, cm, w, mu, sigma, erev,
        sw, smu, ssig, serev, out, B, T, d);
}